// Round 12
// baseline (223.909 us; speedup 1.0000x reference)
//
#include <hip/hip_runtime.h>
#include <float.h>
#include <math.h>

#define N_ROWS 4096
#define M_TGT  65536
#define DDIM   256

// ---------------------------------------------------------------------------
// Shared types/helpers
// ---------------------------------------------------------------------------
typedef short bf16x8 __attribute__((ext_vector_type(8)));
typedef float f32x4 __attribute__((ext_vector_type(4)));
typedef unsigned short ushort4_t __attribute__((ext_vector_type(4)));

__device__ inline unsigned short f2bf(float f) {
  union { float f; unsigned u; } c; c.f = f;
  unsigned u = c.u;
  unsigned r = (u + 0x7FFFu + ((u >> 16) & 1u)) >> 16;  // RNE
  return (unsigned short)r;
}

__device__ inline void gload_lds16(const void* g, void* l) {
  __builtin_amdgcn_global_load_lds(
      (const __attribute__((address_space(1))) void*)g,
      (__attribute__((address_space(3))) void*)l, 16, 0, 0);
}

#define MFMA16(a, b, c) __builtin_amdgcn_mfma_f32_16x16x32_bf16(a, b, c, 0, 0, 0)

// ---------------------------------------------------------------------------
// Fused fp32->bf16 convert + row norm for BOTH x and t. One wave per row.
// ---------------------------------------------------------------------------
__global__ __launch_bounds__(256) void conv_norm_all(
    const float* __restrict__ x, const float* __restrict__ t,
    unsigned short* __restrict__ xb, unsigned short* __restrict__ tb,
    float* __restrict__ xn, float* __restrict__ tn) {
  int wave = threadIdx.x >> 6;
  int lane = threadIdx.x & 63;
  int row  = blockIdx.x * 4 + wave;
  const float* src;
  unsigned short* db;
  float* dn;
  if (row < N_ROWS) {
    src = x + (size_t)row * DDIM;
    db  = xb + (size_t)row * DDIM;
    dn  = xn + row;
  } else {
    int r = row - N_ROWS;
    if (r >= M_TGT) return;
    src = t + (size_t)r * DDIM;
    db  = tb + (size_t)r * DDIM;
    dn  = tn + r;
  }
  float4 v = *(const float4*)(src + lane * 4);
  float ss = v.x * v.x + v.y * v.y + v.z * v.z + v.w * v.w;
  ushort4_t o;
  o[0] = f2bf(v.x); o[1] = f2bf(v.y); o[2] = f2bf(v.z); o[3] = f2bf(v.w);
  *(ushort4_t*)(db + lane * 4) = o;
  #pragma unroll
  for (int off = 32; off > 0; off >>= 1) ss += __shfl_xor(ss, off, 64);
  if (lane == 0) *dn = ss;
}

// ---------------------------------------------------------------------------
// bf16 MFMA screening GEMM — r10 body with ROTATED K-loop.
// 128x256 tile, 8 waves, BK=64, SINGLE 48 KB buffer, 3 blocks/CU.
// Loop order per K-step: ds_read frags -> __syncthreads (reads done, buffer
// free; vmcnt drain is free here) -> stage(t+1) into same buffer -> MFMA on
// regs (covers the stage flight) -> loop-top __syncthreads (vmcnt drain now
// lands ~600 cyc after issue instead of 0 — r10's exposed-latency fix).
// Swizzle (r3/r10-proven 0-conflict): 128B rows = 8 x 16B slots, phys
// p = s ^ (row&7); stage source pre-permuted with same involution (rule 21).
// t is the MFMA A-operand: C-rows (lane-local cg*4+j) are TARGET cols;
// per-32-col group min = per-thread fmin chain + 2 shfl_xor.
// Output: bmv32[row][2048] group mins (identical layout to r9/r10).
// ---------------------------------------------------------------------------
#define GBM 128                    // x rows per block
#define GBN2 256                   // t cols per block
#define GBK 64
#define NCB 512                    // 128-col tiles (mid path)
#define NGRP 2048                  // 32-col groups
#define MARGIN 1.5f

__global__ __launch_bounds__(512) void nn_gemm_bf16(
    const unsigned short* __restrict__ xb, const unsigned short* __restrict__ tb,
    const float* __restrict__ tn, float* __restrict__ bmv32) {
  __shared__ __align__(16) unsigned short sX[GBM * GBK];    // 16 KB (x rows)
  __shared__ __align__(16) unsigned short sT[GBN2 * GBK];   // 32 KB (t rows)
  __shared__ float smin[8][128];                            // 4 KB

  const int tid  = threadIdx.x;
  const int lane = tid & 63;
  const int wid  = tid >> 6;        // 0..7
  const int wt   = wid >> 1;        // t quarter (64 cols each)
  const int wx   = wid & 1;         // x half (64 rows each)
  const int ln   = lane & 15;
  const int cg   = lane >> 4;

  // XCD-aware, t-panel-reuse ordering (bijective: 8192 = 8 * 32 rb * 32 cbq)
  const int bid = blockIdx.x;
  const int xcd = bid & 7;
  const int w   = bid >> 3;
  const int rb  = w & 31;                    // fastest within XCD
  const int cb  = xcd * 32 + (w >> 5);       // 0..255 (256-col tiles)
  const int row0 = rb * GBM;
  const int col0 = cb * GBN2;

  // staging maps (proven): chunk q -> row=q>>3, phys slot=q&7,
  // logical slot s = (q&7) ^ (row&7); source k-offset = s*8
  int rqa[2], sqa[2];
  #pragma unroll
  for (int i = 0; i < 2; ++i) {
    int q = i * 512 + tid;
    rqa[i] = q >> 3;
    sqa[i] = (q & 7) ^ (rqa[i] & 7);
  }
  int rqb[4], sqb[4];
  #pragma unroll
  for (int i = 0; i < 4; ++i) {
    int q = i * 512 + tid;
    rqb[i] = q >> 3;
    sqb[i] = (q & 7) ^ (rqb[i] & 7);
  }
  char* sXc = (char*)sX;
  char* sTc = (char*)sT;

  f32x4 acc[4][4];
  const f32x4 zero = {0.0f, 0.0f, 0.0f, 0.0f};
  #pragma unroll
  for (int m = 0; m < 4; ++m)
    #pragma unroll
    for (int n = 0; n < 4; ++n) acc[m][n] = zero;

  // prologue: stage K-step 0
  #pragma unroll
  for (int i = 0; i < 2; ++i)
    gload_lds16(xb + (size_t)(row0 + rqa[i]) * DDIM + sqa[i] * 8,
                sXc + (i * 512 + tid) * 16);
  #pragma unroll
  for (int i = 0; i < 4; ++i)
    gload_lds16(tb + (size_t)(col0 + rqb[i]) * DDIM + sqb[i] * 8,
                sTc + (i * 512 + tid) * 16);

  #pragma unroll
  for (int t = 0; t < 4; ++t) {
    const int kc = t * GBK;
    __syncthreads();   // stages for this step complete (vmcnt drain covered
                       // by previous step's MFMA; t=0: prologue drain)

    // fragment reads from the single buffer
    bf16x8 tf[4][2], xf[4][2];
    #pragma unroll
    for (int m = 0; m < 4; ++m) {
      int r = wt * 64 + m * 16 + ln;
      #pragma unroll
      for (int kk = 0; kk < 2; ++kk) {
        int p = (kk * 4 + cg) ^ (r & 7);
        tf[m][kk] = *(const bf16x8*)(sTc + r * 128 + p * 16);
      }
    }
    #pragma unroll
    for (int n = 0; n < 4; ++n) {
      int r = wx * 64 + n * 16 + ln;
      #pragma unroll
      for (int kk = 0; kk < 2; ++kk) {
        int p = (kk * 4 + cg) ^ (r & 7);
        xf[n][kk] = *(const bf16x8*)(sXc + r * 128 + p * 16);
      }
    }
    __syncthreads();   // all waves' reads in regs -> buffer free (lgkm drain
                       // needed anyway before MFMA; vmcnt is 0 here = free)

    // stage NEXT K-step into the same buffer (overlaps with MFMA below)
    if (t < 3) {
      #pragma unroll
      for (int i = 0; i < 2; ++i)
        gload_lds16(xb + (size_t)(row0 + rqa[i]) * DDIM + kc + GBK + sqa[i] * 8,
                    sXc + (i * 512 + tid) * 16);
      #pragma unroll
      for (int i = 0; i < 4; ++i)
        gload_lds16(tb + (size_t)(col0 + rqb[i]) * DDIM + kc + GBK + sqb[i] * 8,
                    sTc + (i * 512 + tid) * 16);
    }

    // MFMA cluster on registers (covers the stage flight)
    __builtin_amdgcn_s_setprio(1);
    #pragma unroll
    for (int kk = 0; kk < 2; ++kk)
      #pragma unroll
      for (int m = 0; m < 4; ++m)
        #pragma unroll
        for (int n = 0; n < 4; ++n)
          acc[m][n] = MFMA16(tf[m][kk], xf[n][kk], acc[m][n]);
    __builtin_amdgcn_s_setprio(0);
  }

  // ---- epilogue: per-thread min per 32-col group (m-pair), per x-row ----
  float tnc[4][4];
  #pragma unroll
  for (int m = 0; m < 4; ++m)
    #pragma unroll
    for (int j = 0; j < 4; ++j)
      tnc[m][j] = tn[col0 + wt * 64 + m * 16 + cg * 4 + j];

  float vres[2][4];
  #pragma unroll
  for (int mh2 = 0; mh2 < 2; ++mh2) {
    #pragma unroll
    for (int n = 0; n < 4; ++n) {
      float v = FLT_MAX;
      #pragma unroll
      for (int mi = 0; mi < 2; ++mi) {
        int m = mh2 * 2 + mi;
        #pragma unroll
        for (int j = 0; j < 4; ++j)
          v = fminf(v, fmaf(-2.0f, acc[m][n][j], tnc[m][j]));
      }
      v = fminf(v, __shfl_xor(v, 16, 64));   // reduce over cg bit 0
      v = fminf(v, __shfl_xor(v, 32, 64));   // reduce over cg bit 1
      vres[mh2][n] = v;
    }
  }

  __syncthreads();                  // done with sX/sT as tiles
  if (cg == 0) {
    #pragma unroll
    for (int mh2 = 0; mh2 < 2; ++mh2)
      #pragma unroll
      for (int n = 0; n < 4; ++n)
        smin[wt * 2 + mh2][wx * 64 + n * 16 + ln] = vres[mh2][n];
  }
  __syncthreads();
  if (tid < 128) {
    float4 o0, o1;
    o0.x = smin[0][tid]; o0.y = smin[1][tid];
    o0.z = smin[2][tid]; o0.w = smin[3][tid];
    o1.x = smin[4][tid]; o1.y = smin[5][tid];
    o1.z = smin[6][tid]; o1.w = smin[7][tid];
    float* dst = &bmv32[(size_t)(row0 + tid) * NGRP + (size_t)cb * 8];
    *(float4*)dst = o0;
    *(float4*)(dst + 4) = o1;
  }
}

// ---------------------------------------------------------------------------
// Fine candidate selection + exact fp32 verification. One block per row.
// ---------------------------------------------------------------------------
__global__ __launch_bounds__(256) void nn_exact_fine(
    const float* __restrict__ x, const float* __restrict__ t,
    const float* __restrict__ xn, const float* __restrict__ tn,
    const float* __restrict__ bmv32, float* __restrict__ out) {
  __shared__ float wmin[4];
  __shared__ int   clist[NGRP];
  __shared__ int   cnt;
  __shared__ float rv[256];
  __shared__ int   ri[256];

  const int row = blockIdx.x;
  const int tid = threadIdx.x;
  const float* brow = bmv32 + (size_t)row * NGRP;

  if (tid == 0) cnt = 0;
  float4 v0 = *(const float4*)(brow + tid * 8);
  float4 v1 = *(const float4*)(brow + tid * 8 + 4);
  float lmin = fminf(fminf(fminf(v0.x, v0.y), fminf(v0.z, v0.w)),
                     fminf(fminf(v1.x, v1.y), fminf(v1.z, v1.w)));
  #pragma unroll
  for (int off = 32; off > 0; off >>= 1)
    lmin = fminf(lmin, __shfl_xor(lmin, off, 64));
  if ((tid & 63) == 0) wmin[tid >> 6] = lmin;
  __syncthreads();
  const float thr =
      fminf(fminf(wmin[0], wmin[1]), fminf(wmin[2], wmin[3])) + MARGIN;

  {
    float vv[8] = {v0.x, v0.y, v0.z, v0.w, v1.x, v1.y, v1.z, v1.w};
    #pragma unroll
    for (int k = 0; k < 8; ++k) {
      if (vv[k] <= thr) {
        int p = atomicAdd(&cnt, 1);
        clist[p] = tid * 8 + k;
      }
    }
  }
  __syncthreads();
  const int nc = cnt;

  float best = FLT_MAX;
  int   bidx = 0x7FFFFFFF;
  const float xnr = xn[row];
  const float* xrow = x + (size_t)row * DDIM;

  for (int ci = 0; ci < nc; ci += 8) {
    int slot = ci + (tid >> 5);
    if (slot < nc) {
      int col = clist[slot] * 32 + (tid & 31);
      const float* trow = t + (size_t)col * DDIM;
      float acc = 0.0f;
      // serial k-ascending fp32 FMA chain (deterministic, exact per col)
      for (int kq = 0; kq < DDIM; kq += 4) {
        float4 xv = *(const float4*)(xrow + kq);
        float4 tv = *(const float4*)(trow + kq);
        acc = fmaf(xv.x, tv.x, acc);
        acc = fmaf(xv.y, tv.y, acc);
        acc = fmaf(xv.z, tv.z, acc);
        acc = fmaf(xv.w, tv.w, acc);
      }
      float d2 = xnr + tn[col] - 2.0f * acc;
      if (d2 < best || (d2 == best && col < bidx)) { best = d2; bidx = col; }
    }
  }
  rv[tid] = best; ri[tid] = bidx;
  __syncthreads();
  for (int s = 128; s >= 1; s >>= 1) {
    if (tid < s) {
      float vo = rv[tid + s]; int io = ri[tid + s];
      if (vo < rv[tid] || (vo == rv[tid] && io < ri[tid])) { rv[tid] = vo; ri[tid] = io; }
    }
    __syncthreads();
  }
  if (tid == 0) {
    out[row] = sqrtf(fmaxf(rv[0], 0.0f));
    out[N_ROWS + row] = (float)ri[0];
  }
}

// ---------------------------------------------------------------------------
// MIDDLE path (ws too small for bmv32): r8-proven coarse GEMM + exact.
// ---------------------------------------------------------------------------
#define MGBM 128
#define MGBN 128

__global__ __launch_bounds__(256) void nn_gemm_mid(
    const unsigned short* __restrict__ xb, const unsigned short* __restrict__ tb,
    const float* __restrict__ tn, float* __restrict__ bmv) {
  __shared__ __align__(16) unsigned short sX[MGBM * GBK];
  __shared__ __align__(16) unsigned short sT[MGBN * GBK];
  __shared__ float smin[2][128];

  const int tid  = threadIdx.x;
  const int lane = tid & 63;
  const int wid  = tid >> 6;
  const int wt   = wid >> 1;
  const int wx   = wid & 1;
  const int ln   = lane & 15;
  const int cg   = lane >> 4;

  const int bid = blockIdx.x;
  const int xcd = bid & 7;
  const int wgi = bid >> 3;
  const int rb  = wgi & 31;
  const int cb  = xcd * 64 + (wgi >> 5);
  const int row0 = rb * MGBM;
  const int col0 = cb * MGBN;

  int rq[4], sq[4];
  #pragma unroll
  for (int i = 0; i < 4; ++i) {
    int q = i * 256 + tid;
    rq[i] = q >> 3;
    sq[i] = (q & 7) ^ (rq[i] & 7);
  }
  char* sXc = (char*)sX;
  char* sTc = (char*)sT;

  f32x4 acc[4][4];
  const f32x4 zero = {0.0f, 0.0f, 0.0f, 0.0f};
  #pragma unroll
  for (int m = 0; m < 4; ++m)
    #pragma unroll
    for (int n = 0; n < 4; ++n) acc[m][n] = zero;

  #pragma unroll
  for (int kc = 0; kc < DDIM; kc += GBK) {
    __syncthreads();
    #pragma unroll
    for (int i = 0; i < 4; ++i)
      gload_lds16(xb + (size_t)(row0 + rq[i]) * DDIM + kc + sq[i] * 8,
                  sXc + i * 4096 + wid * 1024);
    #pragma unroll
    for (int i = 0; i < 4; ++i)
      gload_lds16(tb + (size_t)(col0 + rq[i]) * DDIM + kc + sq[i] * 8,
                  sTc + i * 4096 + wid * 1024);
    __syncthreads();

    bf16x8 tf[4][2], xf[4][2];
    #pragma unroll
    for (int m = 0; m < 4; ++m) {
      int r = wt * 64 + m * 16 + ln;
      #pragma unroll
      for (int kk = 0; kk < 2; ++kk) {
        int p = (kk * 4 + cg) ^ (r & 7);
        tf[m][kk] = *(const bf16x8*)(sTc + r * 128 + p * 16);
      }
    }
    #pragma unroll
    for (int n = 0; n < 4; ++n) {
      int r = wx * 64 + n * 16 + ln;
      #pragma unroll
      for (int kk = 0; kk < 2; ++kk) {
        int p = (kk * 4 + cg) ^ (r & 7);
        xf[n][kk] = *(const bf16x8*)(sXc + r * 128 + p * 16);
      }
    }
    #pragma unroll
    for (int kk = 0; kk < 2; ++kk)
      #pragma unroll
      for (int m = 0; m < 4; ++m)
        #pragma unroll
        for (int n = 0; n < 4; ++n)
          acc[m][n] = MFMA16(tf[m][kk], xf[n][kk], acc[m][n]);
  }

  float tnc[4][4];
  #pragma unroll
  for (int m = 0; m < 4; ++m)
    #pragma unroll
    for (int j = 0; j < 4; ++j)
      tnc[m][j] = tn[col0 + wt * 64 + m * 16 + cg * 4 + j];

  float res[4];
  #pragma unroll
  for (int n = 0; n < 4; ++n) {
    float v = FLT_MAX;
    #pragma unroll
    for (int m = 0; m < 4; ++m)
      #pragma unroll
      for (int j = 0; j < 4; ++j)
        v = fminf(v, fmaf(-2.0f, acc[m][n][j], tnc[m][j]));
    v = fminf(v, __shfl_xor(v, 16, 64));
    v = fminf(v, __shfl_xor(v, 32, 64));
    res[n] = v;
  }

  __syncthreads();
  if (cg == 0) {
    #pragma unroll
    for (int n = 0; n < 4; ++n)
      smin[wt][wx * 64 + n * 16 + ln] = res[n];
  }
  __syncthreads();
  if (tid < 128)
    bmv[(size_t)(row0 + tid) * NCB + cb] = fminf(smin[0][tid], smin[1][tid]);
}

__global__ __launch_bounds__(256) void nn_exact_mid(
    const float* __restrict__ x, const float* __restrict__ t,
    const float* __restrict__ xn, const float* __restrict__ tn,
    const float* __restrict__ bmv, float* __restrict__ out) {
  __shared__ float sv[NCB];
  __shared__ int   clist[NCB];
  __shared__ int   cnt;
  __shared__ float wmin[4];
  __shared__ float rv[256];
  __shared__ int   ri[256];

  const int row = blockIdx.x;
  const int tid = threadIdx.x;

  if (tid == 0) cnt = 0;
  float lmin = FLT_MAX;
  #pragma unroll
  for (int e = tid; e < NCB; e += 256) {
    float v = bmv[(size_t)row * NCB + e];
    sv[e] = v;
    lmin = fminf(lmin, v);
  }
  #pragma unroll
  for (int off = 32; off > 0; off >>= 1) lmin = fminf(lmin, __shfl_xor(lmin, off, 64));
  if ((tid & 63) == 0) wmin[tid >> 6] = lmin;
  __syncthreads();
  const float g = fminf(fminf(wmin[0], wmin[1]), fminf(wmin[2], wmin[3]));

  #pragma unroll
  for (int e = tid; e < NCB; e += 256) {
    if (sv[e] <= g + MARGIN) {
      int p = atomicAdd(&cnt, 1);
      clist[p] = e;
    }
  }
  __syncthreads();
  const int nc = cnt;

  float best = FLT_MAX;
  int   bidx = 0x7FFFFFFF;
  const float xnr = xn[row];
  const float* xrow = x + (size_t)row * DDIM;

  for (int ci = 0; ci < nc; ci += 2) {
    int slot = ci + (tid >> 7);
    if (slot < nc) {
      int col = clist[slot] * 128 + (tid & 127);
      const float* trow = t + (size_t)col * DDIM;
      float acc = 0.0f;
      for (int kq = 0; kq < DDIM; kq += 4) {
        float4 xv = *(const float4*)(xrow + kq);
        float4 tv = *(const float4*)(trow + kq);
        acc = fmaf(xv.x, tv.x, acc);
        acc = fmaf(xv.y, tv.y, acc);
        acc = fmaf(xv.z, tv.z, acc);
        acc = fmaf(xv.w, tv.w, acc);
      }
      float d2 = xnr + tn[col] - 2.0f * acc;
      if (d2 < best || (d2 == best && col < bidx)) { best = d2; bidx = col; }
    }
  }
  rv[tid] = best; ri[tid] = bidx;
  __syncthreads();
  for (int s = 128; s >= 1; s >>= 1) {
    if (tid < s) {
      float vo = rv[tid + s]; int io = ri[tid + s];
      if (vo < rv[tid] || (vo == rv[tid] && io < ri[tid])) { rv[tid] = vo; ri[tid] = io; }
    }
    __syncthreads();
  }
  if (tid == 0) {
    out[row] = sqrtf(fmaxf(rv[0], 0.0f));
    out[N_ROWS + row] = (float)ri[0];
  }
}

// ---------------------------------------------------------------------------
// Fallback fp32 path (if ws tiny) — round-1 proven
// ---------------------------------------------------------------------------
#define BM 64
#define BN 64
#define KC 16
#define S_STRIPS 32
#define PADM 68

__global__ __launch_bounds__(256) void norms_kernel_fb(
    const float* __restrict__ x, const float* __restrict__ t,
    float* __restrict__ xn, float* __restrict__ tn) {
  int wave = threadIdx.x >> 6;
  int lane = threadIdx.x & 63;
  int row  = blockIdx.x * 4 + wave;
  const float* src; float* dst;
  if (row < N_ROWS) { src = x + (size_t)row * DDIM; dst = xn + row; }
  else {
    int r = row - N_ROWS;
    if (r >= M_TGT) return;
    src = t + (size_t)r * DDIM; dst = tn + r;
  }
  float4 v = *(const float4*)(src + lane * 4);
  float s = v.x * v.x + v.y * v.y + v.z * v.z + v.w * v.w;
  #pragma unroll
  for (int off = 32; off > 0; off >>= 1) s += __shfl_xor(s, off, 64);
  if (lane == 0) *dst = s;
}

__global__ __launch_bounds__(256) void nn_main_fb(
    const float* __restrict__ x, const float* __restrict__ t,
    const float* __restrict__ xn, const float* __restrict__ tn,
    float* __restrict__ pmin, int* __restrict__ pidx) {
  __shared__ float sx[KC][PADM];
  __shared__ float st[KC][PADM];
  const int tid = threadIdx.x;
  const int rb = blockIdx.x;
  const int strip = blockIdx.y;
  const int tx = tid & 15, ty = tid >> 4;
  const int row0 = rb * BM;
  const int col_start = strip * (M_TGT / S_STRIPS);
  const int ntiles = (M_TGT / S_STRIPS) / BN;
  const int srow = tid >> 2;
  const int kq = (tid & 3) * 4;

  float runMin[4]; int runIdx[4];
  #pragma unroll
  for (int r = 0; r < 4; ++r) { runMin[r] = FLT_MAX; runIdx[r] = 0; }
  float xnr[4];
  #pragma unroll
  for (int r = 0; r < 4; ++r) xnr[r] = xn[row0 + ty * 4 + r];

  for (int tile = 0; tile < ntiles; ++tile) {
    const int cbk = col_start + tile * BN;
    float acc[4][4];
    #pragma unroll
    for (int r = 0; r < 4; ++r)
      #pragma unroll
      for (int c = 0; c < 4; ++c) acc[r][c] = 0.0f;
    #pragma unroll 1
    for (int kc = 0; kc < DDIM; kc += KC) {
      float4 xv = *(const float4*)(x + (size_t)(row0 + srow) * DDIM + kc + kq);
      float4 tv = *(const float4*)(t + (size_t)(cbk + srow) * DDIM + kc + kq);
      __syncthreads();
      sx[kq + 0][srow] = xv.x; sx[kq + 1][srow] = xv.y;
      sx[kq + 2][srow] = xv.z; sx[kq + 3][srow] = xv.w;
      st[kq + 0][srow] = tv.x; st[kq + 1][srow] = tv.y;
      st[kq + 2][srow] = tv.z; st[kq + 3][srow] = tv.w;
      __syncthreads();
      #pragma unroll
      for (int k = 0; k < KC; ++k) {
        float4 xa = *(const float4*)&sx[k][ty * 4];
        float4 tb2 = *(const float4*)&st[k][tx * 4];
        float xr[4] = {xa.x, xa.y, xa.z, xa.w};
        float tc[4] = {tb2.x, tb2.y, tb2.z, tb2.w};
        #pragma unroll
        for (int r = 0; r < 4; ++r)
          #pragma unroll
          for (int c = 0; c < 4; ++c)
            acc[r][c] = fmaf(xr[r], tc[c], acc[r][c]);
      }
    }
    #pragma unroll
    for (int r = 0; r < 4; ++r)
      #pragma unroll
      for (int c = 0; c < 4; ++c) {
        int col = cbk + tx * 4 + c;
        float d2 = xnr[r] + tn[col] - 2.0f * acc[r][c];
        if (d2 < runMin[r]) { runMin[r] = d2; runIdx[r] = col; }
      }
  }
  __syncthreads();
  float* redv = &sx[0][0];
  int*   redi = (int*)&st[0][0];
  #pragma unroll
  for (int r = 0; r < 4; ++r) {
    int lrow = ty * 4 + r;
    redv[lrow * 16 + tx] = runMin[r];
    redi[lrow * 16 + tx] = runIdx[r];
  }
  __syncthreads();
  if (tid < 64) {
    float best = FLT_MAX; int bi = 0;
    #pragma unroll
    for (int j = 0; j < 16; ++j) {
      float v = redv[tid * 16 + j];
      int   i = redi[tid * 16 + j];
      if (v < best || (v == best && i < bi)) { best = v; bi = i; }
    }
    int grow = row0 + tid;
    pmin[(size_t)grow * S_STRIPS + strip] = best;
    pidx[(size_t)grow * S_STRIPS + strip] = bi;
  }
}

__global__ __launch_bounds__(256) void reduce_final_fb(
    const float* __restrict__ pmin, const int* __restrict__ pidx,
    float* __restrict__ out) {
  int row = blockIdx.x * 256 + threadIdx.x;
  if (row >= N_ROWS) return;
  float best = FLT_MAX; int bi = 0;
  #pragma unroll 4
  for (int s = 0; s < S_STRIPS; ++s) {
    float v = pmin[(size_t)row * S_STRIPS + s];
    int   i = pidx[(size_t)row * S_STRIPS + s];
    if (v < best || (v == best && i < bi)) { best = v; bi = i; }
  }
  out[row] = sqrtf(fmaxf(best, 0.0f));
  out[N_ROWS + row] = (float)bi;
}

// ---------------------------------------------------------------------------
extern "C" void kernel_launch(void* const* d_in, const int* in_sizes, int n_in,
                              void* d_out, int out_size, void* d_ws, size_t ws_size,
                              hipStream_t stream) {
  const float* x = (const float*)d_in[0];
  const float* t = (const float*)d_in[1];
  float* ws = (float*)d_ws;
  float* out = (float*)d_out;

  float* xn = ws;                       // 4096
  float* tn = ws + N_ROWS;              // 65536

  // FINE path ws layout (floats): xn | tn | bmv32[4096*2048] | xb | tb
  const size_t f_bmvF = (size_t)N_ROWS + M_TGT;
  const size_t f_xbF  = f_bmvF + (size_t)N_ROWS * NGRP;
  const size_t f_tbF  = f_xbF + ((size_t)N_ROWS * DDIM) / 2;
  const size_t need_fine = (f_tbF + ((size_t)M_TGT * DDIM) / 2) * sizeof(float);

  // MID path ws layout (floats): xn | tn | bmv[4096*512] | xb | tb
  const size_t f_bmvM = (size_t)N_ROWS + M_TGT;
  const size_t f_xbM  = f_bmvM + (size_t)N_ROWS * NCB;
  const size_t f_tbM  = f_xbM + ((size_t)N_ROWS * DDIM) / 2;
  const size_t need_mid = (f_tbM + ((size_t)M_TGT * DDIM) / 2) * sizeof(float);

  if (ws_size >= need_fine) {
    float* bmv32 = ws + f_bmvF;
    unsigned short* xb = (unsigned short*)(ws + f_xbF);
    unsigned short* tb = (unsigned short*)(ws + f_tbF);

    conv_norm_all<<<(N_ROWS + M_TGT) / 4, 256, 0, stream>>>(x, t, xb, tb, xn, tn);
    nn_gemm_bf16<<<(N_ROWS / GBM) * (M_TGT / GBN2), 512, 0, stream>>>(xb, tb, tn, bmv32);
    nn_exact_fine<<<N_ROWS, 256, 0, stream>>>(x, t, xn, tn, bmv32, out);
  } else if (ws_size >= need_mid) {
    float* bmv = ws + f_bmvM;
    unsigned short* xb = (unsigned short*)(ws + f_xbM);
    unsigned short* tb = (unsigned short*)(ws + f_tbM);

    conv_norm_all<<<(N_ROWS + M_TGT) / 4, 256, 0, stream>>>(x, t, xb, tb, xn, tn);
    nn_gemm_mid<<<(N_ROWS / MGBM) * NCB, 256, 0, stream>>>(xb, tb, tn, bmv);
    nn_exact_mid<<<N_ROWS, 256, 0, stream>>>(x, t, xn, tn, bmv, out);
  } else {
    norms_kernel_fb<<<(N_ROWS + M_TGT) / 4, 256, 0, stream>>>(x, t, xn, tn);
    float* pmin = ws + N_ROWS + M_TGT;
    int*   pidx = (int*)(ws + N_ROWS + M_TGT + (size_t)N_ROWS * S_STRIPS);
    dim3 grid(N_ROWS / BM, S_STRIPS);
    nn_main_fb<<<grid, 256, 0, stream>>>(x, t, xn, tn, pmin, pidx);
    reduce_final_fb<<<(N_ROWS + 255) / 256, 256, 0, stream>>>(pmin, pidx, out);
  }
}

// Round 13
// 190.892 us; speedup vs baseline: 1.1730x; 1.1730x over previous
//
#include <hip/hip_runtime.h>
#include <float.h>
#include <math.h>

#define N_ROWS 4096
#define M_TGT  65536
#define DDIM   256

// ---------------------------------------------------------------------------
// Shared types/helpers
// ---------------------------------------------------------------------------
typedef short bf16x8 __attribute__((ext_vector_type(8)));
typedef float f32x4 __attribute__((ext_vector_type(4)));
typedef unsigned short ushort4_t __attribute__((ext_vector_type(4)));

__device__ inline unsigned short f2bf(float f) {
  union { float f; unsigned u; } c; c.f = f;
  unsigned u = c.u;
  unsigned r = (u + 0x7FFFu + ((u >> 16) & 1u)) >> 16;  // RNE
  return (unsigned short)r;
}

__device__ inline void gload_lds16(const void* g, void* l) {
  __builtin_amdgcn_global_load_lds(
      (const __attribute__((address_space(1))) void*)g,
      (__attribute__((address_space(3))) void*)l, 16, 0, 0);
}

#define MFMA16(a, b, c) __builtin_amdgcn_mfma_f32_16x16x32_bf16(a, b, c, 0, 0, 0)

// ---------------------------------------------------------------------------
// Fused fp32->bf16 convert + row norm for BOTH x and t. One wave per row.
// ---------------------------------------------------------------------------
__global__ __launch_bounds__(256) void conv_norm_all(
    const float* __restrict__ x, const float* __restrict__ t,
    unsigned short* __restrict__ xb, unsigned short* __restrict__ tb,
    float* __restrict__ xn, float* __restrict__ tn) {
  int wave = threadIdx.x >> 6;
  int lane = threadIdx.x & 63;
  int row  = blockIdx.x * 4 + wave;
  const float* src;
  unsigned short* db;
  float* dn;
  if (row < N_ROWS) {
    src = x + (size_t)row * DDIM;
    db  = xb + (size_t)row * DDIM;
    dn  = xn + row;
  } else {
    int r = row - N_ROWS;
    if (r >= M_TGT) return;
    src = t + (size_t)r * DDIM;
    db  = tb + (size_t)r * DDIM;
    dn  = tn + r;
  }
  float4 v = *(const float4*)(src + lane * 4);
  float ss = v.x * v.x + v.y * v.y + v.z * v.z + v.w * v.w;
  ushort4_t o;
  o[0] = f2bf(v.x); o[1] = f2bf(v.y); o[2] = f2bf(v.z); o[3] = f2bf(v.w);
  *(ushort4_t*)(db + lane * 4) = o;
  #pragma unroll
  for (int off = 32; off > 0; off >>= 1) ss += __shfl_xor(ss, off, 64);
  if (lane == 0) *dn = ss;
}

// ---------------------------------------------------------------------------
// bf16 MFMA screening GEMM — r10 configuration (best measured: 145 us,
// 944 TF, MfmaUtil 43%, 0 bank conflicts, 3 blocks/CU).
// 128x256 tile, 8 waves (4 wt x 2 wx), BK=64, single-buffered 48 KB LDS.
// Ingredients (each proven by within-session A/B):
//  - operand-swapped epilogue (r8, +46us): t is the MFMA A-operand so C-rows
//    (lane-local cg*4+j) are TARGET cols; min-over-targets is a per-thread
//    fmin chain + 2 shfl_xor instead of a 64-shfl cross-lane reduce.
//  - fine 32-col screen groups (r9): 4x less exact-verify traffic.
//  - 0-conflict XOR LDS layout (r3): 128B rows = 8 x 16B slots, phys slot
//    p = s ^ (row&7); stage source pre-permuted (rule 21 both-sides).
//  - XCD-aware t-panel-reuse block order; 128x256 halves per-FLOP overheads
//    vs 128^2 (r10).
// Schedule notes: r11 (BK=32 dbuf 2-phase) and r12 (rotated loop) both
// REGRESSED — K=256 gives only 4 K-steps, too shallow for any deep pipeline;
// this 2-barrier structure at 3 blocks/CU is the measured plateau.
// Output: bmv32[row][2048] 32-col group mins.
// ---------------------------------------------------------------------------
#define GBM 128                    // x rows per block
#define GBN2 256                   // t cols per block
#define GBK 64
#define NCB 512                    // 128-col tiles (mid path)
#define NGRP 2048                  // 32-col groups
#define MARGIN 1.5f

__global__ __launch_bounds__(512) void nn_gemm_bf16(
    const unsigned short* __restrict__ xb, const unsigned short* __restrict__ tb,
    const float* __restrict__ tn, float* __restrict__ bmv32) {
  __shared__ __align__(16) unsigned short sX[GBM * GBK];    // 16 KB (x rows)
  __shared__ __align__(16) unsigned short sT[GBN2 * GBK];   // 32 KB (t rows)
  __shared__ float smin[8][128];                            // 4 KB

  const int tid  = threadIdx.x;
  const int lane = tid & 63;
  const int wid  = tid >> 6;        // 0..7
  const int wt   = wid >> 1;        // t quarter (64 cols each)
  const int wx   = wid & 1;         // x half (64 rows each)
  const int ln   = lane & 15;
  const int cg   = lane >> 4;

  // XCD-aware, t-panel-reuse ordering (bijective: 8192 = 8 * 32 rb * 32 cbq)
  const int bid = blockIdx.x;
  const int xcd = bid & 7;
  const int w   = bid >> 3;
  const int rb  = w & 31;                    // fastest within XCD
  const int cb  = xcd * 32 + (w >> 5);       // 0..255 (256-col tiles)
  const int row0 = rb * GBM;
  const int col0 = cb * GBN2;

  // staging maps (proven): chunk q -> row=q>>3, phys slot=q&7,
  // logical slot s = (q&7) ^ (row&7); source k-offset = s*8
  int rqa[2], sqa[2];
  #pragma unroll
  for (int i = 0; i < 2; ++i) {
    int q = i * 512 + tid;
    rqa[i] = q >> 3;
    sqa[i] = (q & 7) ^ (rqa[i] & 7);
  }
  int rqb[4], sqb[4];
  #pragma unroll
  for (int i = 0; i < 4; ++i) {
    int q = i * 512 + tid;
    rqb[i] = q >> 3;
    sqb[i] = (q & 7) ^ (rqb[i] & 7);
  }
  char* sXc = (char*)sX;
  char* sTc = (char*)sT;

  f32x4 acc[4][4];
  const f32x4 zero = {0.0f, 0.0f, 0.0f, 0.0f};
  #pragma unroll
  for (int m = 0; m < 4; ++m)
    #pragma unroll
    for (int n = 0; n < 4; ++n) acc[m][n] = zero;

  #pragma unroll
  for (int kc = 0; kc < DDIM; kc += GBK) {
    __syncthreads();   // previous step's LDS reads complete
    #pragma unroll
    for (int i = 0; i < 2; ++i)
      gload_lds16(xb + (size_t)(row0 + rqa[i]) * DDIM + kc + sqa[i] * 8,
                  sXc + (i * 512 + tid) * 16);
    #pragma unroll
    for (int i = 0; i < 4; ++i)
      gload_lds16(tb + (size_t)(col0 + rqb[i]) * DDIM + kc + sqb[i] * 8,
                  sTc + (i * 512 + tid) * 16);
    __syncthreads();   // vmcnt(0) drained before barrier -> data ready

    bf16x8 tf[4][2], xf[4][2];
    #pragma unroll
    for (int m = 0; m < 4; ++m) {
      int r = wt * 64 + m * 16 + ln;
      #pragma unroll
      for (int kk = 0; kk < 2; ++kk) {
        int p = (kk * 4 + cg) ^ (r & 7);
        tf[m][kk] = *(const bf16x8*)(sTc + r * 128 + p * 16);
      }
    }
    #pragma unroll
    for (int n = 0; n < 4; ++n) {
      int r = wx * 64 + n * 16 + ln;
      #pragma unroll
      for (int kk = 0; kk < 2; ++kk) {
        int p = (kk * 4 + cg) ^ (r & 7);
        xf[n][kk] = *(const bf16x8*)(sXc + r * 128 + p * 16);
      }
    }
    #pragma unroll
    for (int kk = 0; kk < 2; ++kk)
      #pragma unroll
      for (int m = 0; m < 4; ++m)
        #pragma unroll
        for (int n = 0; n < 4; ++n)
          acc[m][n] = MFMA16(tf[m][kk], xf[n][kk], acc[m][n]);
  }

  // ---- epilogue: per-thread min per 32-col group (m-pair), per x-row ----
  float tnc[4][4];
  #pragma unroll
  for (int m = 0; m < 4; ++m)
    #pragma unroll
    for (int j = 0; j < 4; ++j)
      tnc[m][j] = tn[col0 + wt * 64 + m * 16 + cg * 4 + j];

  float vres[2][4];
  #pragma unroll
  for (int mh2 = 0; mh2 < 2; ++mh2) {
    #pragma unroll
    for (int n = 0; n < 4; ++n) {
      float v = FLT_MAX;
      #pragma unroll
      for (int mi = 0; mi < 2; ++mi) {
        int m = mh2 * 2 + mi;
        #pragma unroll
        for (int j = 0; j < 4; ++j)
          v = fminf(v, fmaf(-2.0f, acc[m][n][j], tnc[m][j]));
      }
      v = fminf(v, __shfl_xor(v, 16, 64));   // reduce over cg bit 0
      v = fminf(v, __shfl_xor(v, 32, 64));   // reduce over cg bit 1
      vres[mh2][n] = v;
    }
  }

  if (cg == 0) {
    #pragma unroll
    for (int mh2 = 0; mh2 < 2; ++mh2)
      #pragma unroll
      for (int n = 0; n < 4; ++n)
        smin[wt * 2 + mh2][wx * 64 + n * 16 + ln] = vres[mh2][n];
  }
  __syncthreads();
  if (tid < 128) {
    float4 o0, o1;
    o0.x = smin[0][tid]; o0.y = smin[1][tid];
    o0.z = smin[2][tid]; o0.w = smin[3][tid];
    o1.x = smin[4][tid]; o1.y = smin[5][tid];
    o1.z = smin[6][tid]; o1.w = smin[7][tid];
    float* dst = &bmv32[(size_t)(row0 + tid) * NGRP + (size_t)cb * 8];
    *(float4*)dst = o0;
    *(float4*)(dst + 4) = o1;
  }
}

// ---------------------------------------------------------------------------
// Fine candidate selection + exact fp32 verification. One block per row.
// Scan 2048 group-mins (8 KB contiguous), verify candidate 32-col groups
// (8 groups per pass, 32 threads each).
// ---------------------------------------------------------------------------
__global__ __launch_bounds__(256) void nn_exact_fine(
    const float* __restrict__ x, const float* __restrict__ t,
    const float* __restrict__ xn, const float* __restrict__ tn,
    const float* __restrict__ bmv32, float* __restrict__ out) {
  __shared__ float wmin[4];
  __shared__ int   clist[NGRP];
  __shared__ int   cnt;
  __shared__ float rv[256];
  __shared__ int   ri[256];

  const int row = blockIdx.x;
  const int tid = threadIdx.x;
  const float* brow = bmv32 + (size_t)row * NGRP;

  if (tid == 0) cnt = 0;
  float4 v0 = *(const float4*)(brow + tid * 8);
  float4 v1 = *(const float4*)(brow + tid * 8 + 4);
  float lmin = fminf(fminf(fminf(v0.x, v0.y), fminf(v0.z, v0.w)),
                     fminf(fminf(v1.x, v1.y), fminf(v1.z, v1.w)));
  #pragma unroll
  for (int off = 32; off > 0; off >>= 1)
    lmin = fminf(lmin, __shfl_xor(lmin, off, 64));
  if ((tid & 63) == 0) wmin[tid >> 6] = lmin;
  __syncthreads();
  const float thr =
      fminf(fminf(wmin[0], wmin[1]), fminf(wmin[2], wmin[3])) + MARGIN;

  {
    float vv[8] = {v0.x, v0.y, v0.z, v0.w, v1.x, v1.y, v1.z, v1.w};
    #pragma unroll
    for (int k = 0; k < 8; ++k) {
      if (vv[k] <= thr) {
        int p = atomicAdd(&cnt, 1);
        clist[p] = tid * 8 + k;
      }
    }
  }
  __syncthreads();
  const int nc = cnt;

  float best = FLT_MAX;
  int   bidx = 0x7FFFFFFF;
  const float xnr = xn[row];
  const float* xrow = x + (size_t)row * DDIM;

  for (int ci = 0; ci < nc; ci += 8) {
    int slot = ci + (tid >> 5);
    if (slot < nc) {
      int col = clist[slot] * 32 + (tid & 31);
      const float* trow = t + (size_t)col * DDIM;
      float acc = 0.0f;
      // serial k-ascending fp32 FMA chain (deterministic, exact per col)
      for (int kq = 0; kq < DDIM; kq += 4) {
        float4 xv = *(const float4*)(xrow + kq);
        float4 tv = *(const float4*)(trow + kq);
        acc = fmaf(xv.x, tv.x, acc);
        acc = fmaf(xv.y, tv.y, acc);
        acc = fmaf(xv.z, tv.z, acc);
        acc = fmaf(xv.w, tv.w, acc);
      }
      float d2 = xnr + tn[col] - 2.0f * acc;
      if (d2 < best || (d2 == best && col < bidx)) { best = d2; bidx = col; }
    }
  }
  rv[tid] = best; ri[tid] = bidx;
  __syncthreads();
  for (int s = 128; s >= 1; s >>= 1) {
    if (tid < s) {
      float vo = rv[tid + s]; int io = ri[tid + s];
      if (vo < rv[tid] || (vo == rv[tid] && io < ri[tid])) { rv[tid] = vo; ri[tid] = io; }
    }
    __syncthreads();
  }
  if (tid == 0) {
    out[row] = sqrtf(fmaxf(rv[0], 0.0f));
    out[N_ROWS + row] = (float)ri[0];
  }
}

// ---------------------------------------------------------------------------
// MIDDLE path (ws too small for bmv32): r8-proven coarse GEMM + exact.
// ---------------------------------------------------------------------------
#define MGBM 128
#define MGBN 128

__global__ __launch_bounds__(256) void nn_gemm_mid(
    const unsigned short* __restrict__ xb, const unsigned short* __restrict__ tb,
    const float* __restrict__ tn, float* __restrict__ bmv) {
  __shared__ __align__(16) unsigned short sX[MGBM * GBK];
  __shared__ __align__(16) unsigned short sT[MGBN * GBK];
  __shared__ float smin[2][128];

  const int tid  = threadIdx.x;
  const int lane = tid & 63;
  const int wid  = tid >> 6;
  const int wt   = wid >> 1;
  const int wx   = wid & 1;
  const int ln   = lane & 15;
  const int cg   = lane >> 4;

  const int bid = blockIdx.x;
  const int xcd = bid & 7;
  const int wgi = bid >> 3;
  const int rb  = wgi & 31;
  const int cb  = xcd * 64 + (wgi >> 5);
  const int row0 = rb * MGBM;
  const int col0 = cb * MGBN;

  int rq[4], sq[4];
  #pragma unroll
  for (int i = 0; i < 4; ++i) {
    int q = i * 256 + tid;
    rq[i] = q >> 3;
    sq[i] = (q & 7) ^ (rq[i] & 7);
  }
  char* sXc = (char*)sX;
  char* sTc = (char*)sT;

  f32x4 acc[4][4];
  const f32x4 zero = {0.0f, 0.0f, 0.0f, 0.0f};
  #pragma unroll
  for (int m = 0; m < 4; ++m)
    #pragma unroll
    for (int n = 0; n < 4; ++n) acc[m][n] = zero;

  #pragma unroll
  for (int kc = 0; kc < DDIM; kc += GBK) {
    __syncthreads();
    #pragma unroll
    for (int i = 0; i < 4; ++i)
      gload_lds16(xb + (size_t)(row0 + rq[i]) * DDIM + kc + sq[i] * 8,
                  sXc + i * 4096 + wid * 1024);
    #pragma unroll
    for (int i = 0; i < 4; ++i)
      gload_lds16(tb + (size_t)(col0 + rq[i]) * DDIM + kc + sq[i] * 8,
                  sTc + i * 4096 + wid * 1024);
    __syncthreads();

    bf16x8 tf[4][2], xf[4][2];
    #pragma unroll
    for (int m = 0; m < 4; ++m) {
      int r = wt * 64 + m * 16 + ln;
      #pragma unroll
      for (int kk = 0; kk < 2; ++kk) {
        int p = (kk * 4 + cg) ^ (r & 7);
        tf[m][kk] = *(const bf16x8*)(sTc + r * 128 + p * 16);
      }
    }
    #pragma unroll
    for (int n = 0; n < 4; ++n) {
      int r = wx * 64 + n * 16 + ln;
      #pragma unroll
      for (int kk = 0; kk < 2; ++kk) {
        int p = (kk * 4 + cg) ^ (r & 7);
        xf[n][kk] = *(const bf16x8*)(sXc + r * 128 + p * 16);
      }
    }
    #pragma unroll
    for (int kk = 0; kk < 2; ++kk)
      #pragma unroll
      for (int m = 0; m < 4; ++m)
        #pragma unroll
        for (int n = 0; n < 4; ++n)
          acc[m][n] = MFMA16(tf[m][kk], xf[n][kk], acc[m][n]);
  }

  float tnc[4][4];
  #pragma unroll
  for (int m = 0; m < 4; ++m)
    #pragma unroll
    for (int j = 0; j < 4; ++j)
      tnc[m][j] = tn[col0 + wt * 64 + m * 16 + cg * 4 + j];

  float res[4];
  #pragma unroll
  for (int n = 0; n < 4; ++n) {
    float v = FLT_MAX;
    #pragma unroll
    for (int m = 0; m < 4; ++m)
      #pragma unroll
      for (int j = 0; j < 4; ++j)
        v = fminf(v, fmaf(-2.0f, acc[m][n][j], tnc[m][j]));
    v = fminf(v, __shfl_xor(v, 16, 64));
    v = fminf(v, __shfl_xor(v, 32, 64));
    res[n] = v;
  }

  __syncthreads();
  if (cg == 0) {
    #pragma unroll
    for (int n = 0; n < 4; ++n)
      smin[wt][wx * 64 + n * 16 + ln] = res[n];
  }
  __syncthreads();
  if (tid < 128)
    bmv[(size_t)(row0 + tid) * NCB + cb] = fminf(smin[0][tid], smin[1][tid]);
}

__global__ __launch_bounds__(256) void nn_exact_mid(
    const float* __restrict__ x, const float* __restrict__ t,
    const float* __restrict__ xn, const float* __restrict__ tn,
    const float* __restrict__ bmv, float* __restrict__ out) {
  __shared__ float sv[NCB];
  __shared__ int   clist[NCB];
  __shared__ int   cnt;
  __shared__ float wmin[4];
  __shared__ float rv[256];
  __shared__ int   ri[256];

  const int row = blockIdx.x;
  const int tid = threadIdx.x;

  if (tid == 0) cnt = 0;
  float lmin = FLT_MAX;
  #pragma unroll
  for (int e = tid; e < NCB; e += 256) {
    float v = bmv[(size_t)row * NCB + e];
    sv[e] = v;
    lmin = fminf(lmin, v);
  }
  #pragma unroll
  for (int off = 32; off > 0; off >>= 1) lmin = fminf(lmin, __shfl_xor(lmin, off, 64));
  if ((tid & 63) == 0) wmin[tid >> 6] = lmin;
  __syncthreads();
  const float g = fminf(fminf(wmin[0], wmin[1]), fminf(wmin[2], wmin[3]));

  #pragma unroll
  for (int e = tid; e < NCB; e += 256) {
    if (sv[e] <= g + MARGIN) {
      int p = atomicAdd(&cnt, 1);
      clist[p] = e;
    }
  }
  __syncthreads();
  const int nc = cnt;

  float best = FLT_MAX;
  int   bidx = 0x7FFFFFFF;
  const float xnr = xn[row];
  const float* xrow = x + (size_t)row * DDIM;

  for (int ci = 0; ci < nc; ci += 2) {
    int slot = ci + (tid >> 7);
    if (slot < nc) {
      int col = clist[slot] * 128 + (tid & 127);
      const float* trow = t + (size_t)col * DDIM;
      float acc = 0.0f;
      for (int kq = 0; kq < DDIM; kq += 4) {
        float4 xv = *(const float4*)(xrow + kq);
        float4 tv = *(const float4*)(trow + kq);
        acc = fmaf(xv.x, tv.x, acc);
        acc = fmaf(xv.y, tv.y, acc);
        acc = fmaf(xv.z, tv.z, acc);
        acc = fmaf(xv.w, tv.w, acc);
      }
      float d2 = xnr + tn[col] - 2.0f * acc;
      if (d2 < best || (d2 == best && col < bidx)) { best = d2; bidx = col; }
    }
  }
  rv[tid] = best; ri[tid] = bidx;
  __syncthreads();
  for (int s = 128; s >= 1; s >>= 1) {
    if (tid < s) {
      float vo = rv[tid + s]; int io = ri[tid + s];
      if (vo < rv[tid] || (vo == rv[tid] && io < ri[tid])) { rv[tid] = vo; ri[tid] = io; }
    }
    __syncthreads();
  }
  if (tid == 0) {
    out[row] = sqrtf(fmaxf(rv[0], 0.0f));
    out[N_ROWS + row] = (float)ri[0];
  }
}

// ---------------------------------------------------------------------------
// Fallback fp32 path (if ws tiny) — round-1 proven
// ---------------------------------------------------------------------------
#define BM 64
#define BN 64
#define KC 16
#define S_STRIPS 32
#define PADM 68

__global__ __launch_bounds__(256) void norms_kernel_fb(
    const float* __restrict__ x, const float* __restrict__ t,
    float* __restrict__ xn, float* __restrict__ tn) {
  int wave = threadIdx.x >> 6;
  int lane = threadIdx.x & 63;
  int row  = blockIdx.x * 4 + wave;
  const float* src; float* dst;
  if (row < N_ROWS) { src = x + (size_t)row * DDIM; dst = xn + row; }
  else {
    int r = row - N_ROWS;
    if (r >= M_TGT) return;
    src = t + (size_t)r * DDIM; dst = tn + r;
  }
  float4 v = *(const float4*)(src + lane * 4);
  float s = v.x * v.x + v.y * v.y + v.z * v.z + v.w * v.w;
  #pragma unroll
  for (int off = 32; off > 0; off >>= 1) s += __shfl_xor(s, off, 64);
  if (lane == 0) *dst = s;
}

__global__ __launch_bounds__(256) void nn_main_fb(
    const float* __restrict__ x, const float* __restrict__ t,
    const float* __restrict__ xn, const float* __restrict__ tn,
    float* __restrict__ pmin, int* __restrict__ pidx) {
  __shared__ float sx[KC][PADM];
  __shared__ float st[KC][PADM];
  const int tid = threadIdx.x;
  const int rb = blockIdx.x;
  const int strip = blockIdx.y;
  const int tx = tid & 15, ty = tid >> 4;
  const int row0 = rb * BM;
  const int col_start = strip * (M_TGT / S_STRIPS);
  const int ntiles = (M_TGT / S_STRIPS) / BN;
  const int srow = tid >> 2;
  const int kq = (tid & 3) * 4;

  float runMin[4]; int runIdx[4];
  #pragma unroll
  for (int r = 0; r < 4; ++r) { runMin[r] = FLT_MAX; runIdx[r] = 0; }
  float xnr[4];
  #pragma unroll
  for (int r = 0; r < 4; ++r) xnr[r] = xn[row0 + ty * 4 + r];

  for (int tile = 0; tile < ntiles; ++tile) {
    const int cbk = col_start + tile * BN;
    float acc[4][4];
    #pragma unroll
    for (int r = 0; r < 4; ++r)
      #pragma unroll
      for (int c = 0; c < 4; ++c) acc[r][c] = 0.0f;
    #pragma unroll 1
    for (int kc = 0; kc < DDIM; kc += KC) {
      float4 xv = *(const float4*)(x + (size_t)(row0 + srow) * DDIM + kc + kq);
      float4 tv = *(const float4*)(t + (size_t)(cbk + srow) * DDIM + kc + kq);
      __syncthreads();
      sx[kq + 0][srow] = xv.x; sx[kq + 1][srow] = xv.y;
      sx[kq + 2][srow] = xv.z; sx[kq + 3][srow] = xv.w;
      st[kq + 0][srow] = tv.x; st[kq + 1][srow] = tv.y;
      st[kq + 2][srow] = tv.z; st[kq + 3][srow] = tv.w;
      __syncthreads();
      #pragma unroll
      for (int k = 0; k < KC; ++k) {
        float4 xa = *(const float4*)&sx[k][ty * 4];
        float4 tb2 = *(const float4*)&st[k][tx * 4];
        float xr[4] = {xa.x, xa.y, xa.z, xa.w};
        float tc[4] = {tb2.x, tb2.y, tb2.z, tb2.w};
        #pragma unroll
        for (int r = 0; r < 4; ++r)
          #pragma unroll
          for (int c = 0; c < 4; ++c)
            acc[r][c] = fmaf(xr[r], tc[c], acc[r][c]);
      }
    }
    #pragma unroll
    for (int r = 0; r < 4; ++r)
      #pragma unroll
      for (int c = 0; c < 4; ++c) {
        int col = cbk + tx * 4 + c;
        float d2 = xnr[r] + tn[col] - 2.0f * acc[r][c];
        if (d2 < runMin[r]) { runMin[r] = d2; runIdx[r] = col; }
      }
  }
  __syncthreads();
  float* redv = &sx[0][0];
  int*   redi = (int*)&st[0][0];
  #pragma unroll
  for (int r = 0; r < 4; ++r) {
    int lrow = ty * 4 + r;
    redv[lrow * 16 + tx] = runMin[r];
    redi[lrow * 16 + tx] = runIdx[r];
  }
  __syncthreads();
  if (tid < 64) {
    float best = FLT_MAX; int bi = 0;
    #pragma unroll
    for (int j = 0; j < 16; ++j) {
      float v = redv[tid * 16 + j];
      int   i = redi[tid * 16 + j];
      if (v < best || (v == best && i < bi)) { best = v; bi = i; }
    }
    int grow = row0 + tid;
    pmin[(size_t)grow * S_STRIPS + strip] = best;
    pidx[(size_t)grow * S_STRIPS + strip] = bi;
  }
}

__global__ __launch_bounds__(256) void reduce_final_fb(
    const float* __restrict__ pmin, const int* __restrict__ pidx,
    float* __restrict__ out) {
  int row = blockIdx.x * 256 + threadIdx.x;
  if (row >= N_ROWS) return;
  float best = FLT_MAX; int bi = 0;
  #pragma unroll 4
  for (int s = 0; s < S_STRIPS; ++s) {
    float v = pmin[(size_t)row * S_STRIPS + s];
    int   i = pidx[(size_t)row * S_STRIPS + s];
    if (v < best || (v == best && i < bi)) { best = v; bi = i; }
  }
  out[row] = sqrtf(fmaxf(best, 0.0f));
  out[N_ROWS + row] = (float)bi;
}

// ---------------------------------------------------------------------------
extern "C" void kernel_launch(void* const* d_in, const int* in_sizes, int n_in,
                              void* d_out, int out_size, void* d_ws, size_t ws_size,
                              hipStream_t stream) {
  const float* x = (const float*)d_in[0];
  const float* t = (const float*)d_in[1];
  float* ws = (float*)d_ws;
  float* out = (float*)d_out;

  float* xn = ws;                       // 4096
  float* tn = ws + N_ROWS;              // 65536

  // FINE path ws layout (floats): xn | tn | bmv32[4096*2048] | xb | tb
  const size_t f_bmvF = (size_t)N_ROWS + M_TGT;
  const size_t f_xbF  = f_bmvF + (size_t)N_ROWS * NGRP;
  const size_t f_tbF  = f_xbF + ((size_t)N_ROWS * DDIM) / 2;
  const size_t need_fine = (f_tbF + ((size_t)M_TGT * DDIM) / 2) * sizeof(float);

  // MID path ws layout (floats): xn | tn | bmv[4096*512] | xb | tb
  const size_t f_bmvM = (size_t)N_ROWS + M_TGT;
  const size_t f_xbM  = f_bmvM + (size_t)N_ROWS * NCB;
  const size_t f_tbM  = f_xbM + ((size_t)N_ROWS * DDIM) / 2;
  const size_t need_mid = (f_tbM + ((size_t)M_TGT * DDIM) / 2) * sizeof(float);

  if (ws_size >= need_fine) {
    float* bmv32 = ws + f_bmvF;
    unsigned short* xb = (unsigned short*)(ws + f_xbF);
    unsigned short* tb = (unsigned short*)(ws + f_tbF);

    conv_norm_all<<<(N_ROWS + M_TGT) / 4, 256, 0, stream>>>(x, t, xb, tb, xn, tn);
    nn_gemm_bf16<<<(N_ROWS / GBM) * (M_TGT / GBN2), 512, 0, stream>>>(xb, tb, tn, bmv32);
    nn_exact_fine<<<N_ROWS, 256, 0, stream>>>(x, t, xn, tn, bmv32, out);
  } else if (ws_size >= need_mid) {
    float* bmv = ws + f_bmvM;
    unsigned short* xb = (unsigned short*)(ws + f_xbM);
    unsigned short* tb = (unsigned short*)(ws + f_tbM);

    conv_norm_all<<<(N_ROWS + M_TGT) / 4, 256, 0, stream>>>(x, t, xb, tb, xn, tn);
    nn_gemm_mid<<<(N_ROWS / MGBM) * NCB, 256, 0, stream>>>(xb, tb, tn, bmv);
    nn_exact_mid<<<N_ROWS, 256, 0, stream>>>(x, t, xn, tn, bmv, out);
  } else {
    norms_kernel_fb<<<(N_ROWS + M_TGT) / 4, 256, 0, stream>>>(x, t, xn, tn);
    float* pmin = ws + N_ROWS + M_TGT;
    int*   pidx = (int*)(ws + N_ROWS + M_TGT + (size_t)N_ROWS * S_STRIPS);
    dim3 grid(N_ROWS / BM, S_STRIPS);
    nn_main_fb<<<grid, 256, 0, stream>>>(x, t, xn, tn, pmin, pidx);
    reduce_final_fb<<<(N_ROWS + 255) / 256, 256, 0, stream>>>(pmin, pidx, out);
  }
}